// Round 9
// baseline (167.884 us; speedup 1.0000x reference)
//
#include <hip/hip_runtime.h>
#include <hip/hip_bf16.h>
#include <stdint.h>

// Problem constants (UniformStrideAttention): B=2, S=2048, D=768, H=12, HD=64, STRIDE=8
#define H_   12
#define S_   2048
#define D_   768
#define HD_  64
#define MS_  256   // S_/8 compressed strided keys per head

typedef __bf16 bf16_8 __attribute__((ext_vector_type(8)));
typedef float  f32_4  __attribute__((ext_vector_type(4)));

typedef __attribute__((address_space(1))) void* gas_ptr;
typedef __attribute__((address_space(3))) void* las_ptr;

__device__ __forceinline__ void g2l16(const void* g, void* l) {
  __builtin_amdgcn_global_load_lds((gas_ptr)g, (las_ptr)l, 16, 0, 0);
}

__device__ __forceinline__ f32_4 mfma16(bf16_8 a, bf16_8 b, f32_4 c) {
  return __builtin_amdgcn_mfma_f32_16x16x32_bf16(a, b, c, 0, 0, 0);
}

__device__ __forceinline__ bf16_8 ld8(const __hip_bfloat16* p) {
  return *reinterpret_cast<const bf16_8*>(p);
}

// ---------------------------------------------------------------------------
// Fused fp32 -> bf16 convert for all three GEMM inputs (x, qkv_w, out_w).
// Destinations are CONTIGUOUS in ws (xb | w1b | w2b), so output index == t.
// ---------------------------------------------------------------------------
__global__ __launch_bounds__(256) void cvt3_f32_bf16(
    const float* __restrict__ a, const float* __restrict__ b,
    const float* __restrict__ c, __hip_bfloat16* __restrict__ out,
    int na4, int nb4) {
  const int t = blockIdx.x * 256 + threadIdx.x;
  float4 f;
  if (t < na4)            f = reinterpret_cast<const float4*>(a)[t];
  else if (t < na4 + nb4) f = reinterpret_cast<const float4*>(b)[t - na4];
  else                    f = reinterpret_cast<const float4*>(c)[t - na4 - nb4];
  union { __hip_bfloat16 h[4]; ushort4 u; } p;
  p.h[0] = __float2bfloat16(f.x);
  p.h[1] = __float2bfloat16(f.y);
  p.h[2] = __float2bfloat16(f.z);
  p.h[3] = __float2bfloat16(f.w);
  reinterpret_cast<ushort4*>(out)[t] = p.u;
}

// ---------------------------------------------------------------------------
// QKV GEMM: C[M,N] = A[M,K] * B[N,K]^T + bias[N]  (bf16, fp32 MFMA accum)
// Tile 128x128, BK=32; 4 waves as 2x2 of 64x64; 16x16x32 MFMA (m97 structure).
// Epilogue -> q/k/v row-major [bh][s][d] (coalesced) + compressed
//   Ks[bh][s/8][d] (t==1, s%8==0) + VsT[bh][d][s/8] (t==2, s%8==0).
// ---------------------------------------------------------------------------
__global__ __launch_bounds__(256, 2) void gemm_qkv(
    const __hip_bfloat16* __restrict__ A, const __hip_bfloat16* __restrict__ B,
    const float* __restrict__ bias,
    __hip_bfloat16* __restrict__ O0, __hip_bfloat16* __restrict__ O1,
    __hip_bfloat16* __restrict__ O2, __hip_bfloat16* __restrict__ O3,
    __hip_bfloat16* __restrict__ O4, int K) {
  __shared__ __bf16 sA[128 * 32];
  __shared__ __bf16 sB[128 * 32];
  const int tid  = threadIdx.x;
  const int lane = tid & 63;
  const int wv   = tid >> 6;
  const int m0 = blockIdx.y * 128;
  const int n0 = blockIdx.x * 128;
  const int wr = (wv >> 1) * 64;
  const int wc = (wv & 1) * 64;

  f32_4 acc[4][4] = {};

  const __hip_bfloat16* aS = A + (size_t)(m0 + (tid >> 2)) * K + ((tid & 3) << 3);
  const __hip_bfloat16* bS = B + (size_t)(n0 + (tid >> 2)) * K + ((tid & 3) << 3);
  const size_t half = (size_t)64 * K;
  __bf16* dA  = &sA[tid * 8];
  __bf16* dA2 = &sA[tid * 8 + 2048];
  __bf16* dB  = &sB[tid * 8];
  __bf16* dB2 = &sB[tid * 8 + 2048];

  const int fr = lane & 15;
  const int kq = (lane >> 4) << 3;

  for (int k0 = 0; k0 < K; k0 += 32) {
    g2l16(aS, dA);
    g2l16(aS + half, dA2);
    g2l16(bS, dB);
    g2l16(bS + half, dB2);
    aS += 32;
    bS += 32;
    __syncthreads();
    bf16_8 af[4], bfm[4];
#pragma unroll
    for (int t = 0; t < 4; ++t)
      af[t] = *reinterpret_cast<const bf16_8*>(&sA[(wr + t * 16 + fr) * 32 + kq]);
#pragma unroll
    for (int t = 0; t < 4; ++t)
      bfm[t] = *reinterpret_cast<const bf16_8*>(&sB[(wc + t * 16 + fr) * 32 + kq]);
#pragma unroll
    for (int ti = 0; ti < 4; ++ti)
#pragma unroll
      for (int tj = 0; tj < 4; ++tj)
        acc[ti][tj] = mfma16(af[ti], bfm[tj], acc[ti][tj]);
    __syncthreads();
  }

  // epilogue: C/D layout col=lane&15, row=(lane>>4)*4+reg
  const int crow = (lane >> 4) << 2;
  const int ccol = lane & 15;
#pragma unroll
  for (int ti = 0; ti < 4; ++ti) {
    const int gmb = m0 + wr + ti * 16 + crow;
#pragma unroll
    for (int tj = 0; tj < 4; ++tj) {
      const int gn = n0 + wc + tj * 16 + ccol;
      const float bv = bias[gn];
      const int t   = gn / D_;
      const int rem = gn - t * D_;
      const int hh = rem >> 6, dd = rem & 63;
      __hip_bfloat16* dst = (t == 0) ? O0 : (t == 1) ? O1 : O2;
#pragma unroll
      for (int r = 0; r < 4; ++r) {
        const int gm = gmb + r;
        const int bb = gm >> 11, ss = gm & (S_ - 1);
        const __hip_bfloat16 hv = __float2bfloat16(acc[ti][tj][r] + bv);
        dst[(((size_t)(bb * H_ + hh) << 11) + ss) * HD_ + dd] = hv;
        if (r == 0 && (gmb & 7) == 0) {
          if (t == 1)        // compressed K rows for coalesced strided reads
            O4[(((size_t)(bb * H_ + hh)) * MS_ + (ss >> 3)) * HD_ + dd] = hv;
          else if (t == 2)   // compressed V^T (d-major) for strided PV
            O3[((size_t)(bb * H_ + hh) * HD_ + dd) * MS_ + (ss >> 3)] = hv;
        }
      }
    }
  }
}

// ---------------------------------------------------------------------------
// FUSED attention + output projection.
// Block = 768 threads = 12 waves = all 12 heads of one (batch, 16-row) tile.
// Phase A (per wave, R8 attention verbatim): NO-RESCALE softmax over
//   strided compressed keys (Ks/VsT, coalesced, prefetched) + local band
//   {i-1,i}\{mult of 8} (band V^T frags via 32 early scalar global loads).
//   Normalized bf16 16x64 slice -> shared LDS ctx tile cx[16][768].
// __syncthreads once.
// Phase B: out[16,768] = cx @ W2^T + b2. Wave h covers n in [64h,64h+64):
//   24 K-steps x 4 n-tiles; A-frags ds_read_b128 from cx (2-way alias, free);
//   B-frags ld8 from L2-resident W2. Accumulation order identical to the old
//   gemm_bt<1,64> (24 sequential MFMAs, bias after) -> bit-identical output.
// Eliminates the 4th dispatch and the ctx global round-trip.
// ---------------------------------------------------------------------------
__global__ __launch_bounds__(768) void attn_out(
    const __hip_bfloat16* __restrict__ Q, const __hip_bfloat16* __restrict__ Kb,
    const __hip_bfloat16* __restrict__ Ks, const __hip_bfloat16* __restrict__ Vr,
    const __hip_bfloat16* __restrict__ VsT, const __hip_bfloat16* __restrict__ W2,
    const float* __restrict__ b2, float* __restrict__ out) {
  __shared__ __bf16 pt[12][16 * 40];
  __shared__ __bf16 cx[16][776];         // 16 x 768 ctx tile, padded stride
  const int lane = threadIdx.x & 63;
  const int h    = threadIdx.x >> 6;     // wave index == head
  const int task = blockIdx.x;           // b*128 + qtile
  const int b    = task >> 7;
  const int i0   = (task & 127) << 4;    // first of 16 query rows
  const int bh   = b * H_ + h;
  const int lr   = lane & 15;
  const int quad = lane >> 4;
  const float SC = 0.125f * 1.44269504088896340736f;  // 1/sqrt(64)*log2(e)

  const __hip_bfloat16* Kh  = Kb  + ((size_t)bh << 11) * HD_;
  const __hip_bfloat16* Ksh = Ks  + (size_t)bh * MS_ * HD_;
  const __hip_bfloat16* Vrh = Vr  + ((size_t)bh << 11) * HD_;
  const __hip_bfloat16* Vsh = VsT + (size_t)bh * HD_ * MS_;
  __bf16* ptw = pt[h];

  const int jbase = (i0 >= 8) ? (i0 - 8) : 0;   // local band base (8-aligned)

  // --- early: band V^T fragments via scalar global loads (latency hides
  // behind the strided loop); masked band slots multiply P=0, any finite ok ---
  const __bf16* Vrb = reinterpret_cast<const __bf16*>(Vrh);
  bf16_8 vfb[4];
#pragma unroll
  for (int ct = 0; ct < 4; ++ct)
#pragma unroll
    for (int e = 0; e < 8; ++e) {
      const int j  = jbase + quad * 8 + e;
      const int jr = (j < S_) ? j : (S_ - 1);
      vfb[ct][e] = Vrb[(size_t)jr * HD_ + ct * 16 + lr];
    }
  // --- early: band K fragments from row-major k ---
  bf16_8 kb_[2][2];
#pragma unroll
  for (int t = 0; t < 2; ++t) {
    const int j  = jbase + t * 16 + lr;
    const int jr = (j < S_) ? j : (S_ - 1);
    const __hip_bfloat16* kp = Kh + (size_t)jr * HD_ + quad * 8;
    kb_[t][0] = ld8(kp);
    kb_[t][1] = ld8(kp + 32);
  }

  // Q A-frags: row = i0+lr, k = quad*8 (+32) — held all kernel
  const __hip_bfloat16* qp = Q + (((size_t)bh << 11) + i0 + lr) * HD_ + quad * 8;
  const bf16_8 qf0 = ld8(qp);
  const bf16_8 qf1 = ld8(qp + 32);

  const __bf16 one = (__bf16)1.0f;
  const bf16_8 onesf = {one, one, one, one, one, one, one, one};

  f32_4 Lacc = {}, oacc[4];
#pragma unroll
  for (int ct = 0; ct < 4; ++ct) oacc[ct] = f32_4{0.f, 0.f, 0.f, 0.f};

  const int mmax = (i0 + 15) >> 3;
  const int nstr = (mmax >> 5) + 1;   // strided 32-key chunks

  auto load_str = [&](int c, bf16_8 (&kf)[2][2], bf16_8 (&vf)[4]) {
    const int mb = c << 5;
#pragma unroll
    for (int t = 0; t < 2; ++t) {
      const __hip_bfloat16* kp = Ksh + (size_t)(mb + t * 16 + lr) * HD_ + quad * 8;
      kf[t][0] = ld8(kp);
      kf[t][1] = ld8(kp + 32);
    }
#pragma unroll
    for (int ct = 0; ct < 4; ++ct)
      vf[ct] = ld8(Vsh + (size_t)(ct * 16 + lr) * MS_ + mb + quad * 8);
  };

  auto softmax_pv = [&](f32_4& s0, f32_4& s1, const bf16_8 (&vf)[4]) {
#pragma unroll
    for (int r = 0; r < 4; ++r) {
      const int row = quad * 4 + r;
      ptw[row * 40 + lr]      = (__bf16)__float2bfloat16(s0[r]);
      ptw[row * 40 + 16 + lr] = (__bf16)__float2bfloat16(s1[r]);
    }
    const bf16_8 pf = *reinterpret_cast<const bf16_8*>(&ptw[lr * 40 + quad * 8]);
#pragma unroll
    for (int ct = 0; ct < 4; ++ct) oacc[ct] = mfma16(pf, vf[ct], oacc[ct]);
    Lacc = mfma16(pf, onesf, Lacc);
  };

  // --- strided chunks (prefetched) ---
  bf16_8 kf[2][2], vf[4], kf2[2][2], vf2[4];
  load_str(0, kf, vf);
  for (int c = 0; c < nstr; ++c) {
    const bool more = (c + 1 < nstr);
    if (more) load_str(c + 1, kf2, vf2);
    const int mb = c << 5;

    f32_4 s0 = {}, s1 = {};
    s0 = mfma16(qf0, kf[0][0], s0);
    s0 = mfma16(qf1, kf[0][1], s0);
    s1 = mfma16(qf0, kf[1][0], s1);
    s1 = mfma16(qf1, kf[1][1], s1);

#pragma unroll
    for (int r = 0; r < 4; ++r) {
      const int i = i0 + quad * 4 + r;
      const bool v0 = ((mb + lr) << 3) <= i;
      const bool v1 = ((mb + 16 + lr) << 3) <= i;
      s0[r] = v0 ? exp2f(fminf(s0[r] * SC, 63.f)) : 0.f;
      s1[r] = v1 ? exp2f(fminf(s1[r] * SC, 63.f)) : 0.f;
    }
    softmax_pv(s0, s1, vf);

    if (more) {
#pragma unroll
      for (int t = 0; t < 2; ++t) { kf[t][0] = kf2[t][0]; kf[t][1] = kf2[t][1]; }
#pragma unroll
      for (int ct = 0; ct < 4; ++ct) vf[ct] = vf2[ct];
    }
  }

  // --- local band chunk {i-1,i} \ multiples-of-8 ---
  {
    f32_4 s0 = {}, s1 = {};
    s0 = mfma16(qf0, kb_[0][0], s0);
    s0 = mfma16(qf1, kb_[0][1], s0);
    s1 = mfma16(qf0, kb_[1][0], s1);
    s1 = mfma16(qf1, kb_[1][1], s1);

#pragma unroll
    for (int r = 0; r < 4; ++r) {
      const int i = i0 + quad * 4 + r;
      const int j0 = jbase + lr, j1 = jbase + 16 + lr;
      const bool v0 = (j0 == i || j0 == i - 1) && (j0 & 7);
      const bool v1 = (j1 == i || j1 == i - 1) && (j1 & 7);
      s0[r] = v0 ? exp2f(fminf(s0[r] * SC, 63.f)) : 0.f;
      s1[r] = v1 ? exp2f(fminf(s1[r] * SC, 63.f)) : 0.f;
    }
    softmax_pv(s0, s1, vfb);
  }

  // --- normalize -> shared ctx tile (cols 64h..64h+63) ---
  f32_4 inv;
#pragma unroll
  for (int r = 0; r < 4; ++r) inv[r] = 1.f / Lacc[r];
#pragma unroll
  for (int ct = 0; ct < 4; ++ct)
#pragma unroll
    for (int r = 0; r < 4; ++r)
      cx[quad * 4 + r][h * 64 + ct * 16 + lr] =
          (__bf16)__float2bfloat16(oacc[ct][r] * inv[r]);
  __syncthreads();

  // --- Phase B: out[16,768] = cx @ W2^T + b2; wave h -> n in [64h, 64h+64) ---
  f32_4 oa[4] = {};
  for (int ks = 0; ks < 24; ++ks) {
    const bf16_8 af = *reinterpret_cast<const bf16_8*>(&cx[lr][ks * 32 + quad * 8]);
#pragma unroll
    for (int t = 0; t < 4; ++t) {
      const int n = h * 64 + t * 16 + lr;
      const bf16_8 bf = ld8(W2 + (size_t)n * D_ + ks * 32 + quad * 8);
      oa[t] = mfma16(af, bf, oa[t]);
    }
  }
#pragma unroll
  for (int t = 0; t < 4; ++t) {
    const int n = h * 64 + t * 16 + lr;
    const float bv = b2[n];
#pragma unroll
    for (int r = 0; r < 4; ++r) {
      const int m = i0 + quad * 4 + r;
      out[(size_t)(b * S_ + m) * D_ + n] = oa[t][r] + bv;
    }
  }
}

// ---------------------------------------------------------------------------
extern "C" void kernel_launch(void* const* d_in, const int* in_sizes, int n_in,
                              void* d_out, int out_size, void* d_ws, size_t ws_size,
                              hipStream_t stream) {
  const float* x    = (const float*)d_in[0];  // [B,S,D]    fp32
  const float* qkvw = (const float*)d_in[1];  // [3D,D]     fp32
  const float* qkvb = (const float*)d_in[2];  // [3D]       fp32
  const float* outw = (const float*)d_in[3];  // [D,D]      fp32
  const float* outb = (const float*)d_in[4];  // [D]        fp32
  float* out = (float*)d_out;                 // [B,S,D]    fp32

  const size_t NX  = (size_t)2 * S_ * D_;     // 3,145,728
  const size_t NW1 = (size_t)3 * D_ * D_;     // 1,769,472
  const size_t NW2 = (size_t)D_ * D_;         //   589,824
  const size_t NVS = (size_t)2 * H_ * HD_ * MS_;  // 393,216

  __hip_bfloat16* xb  = (__hip_bfloat16*)d_ws;
  __hip_bfloat16* w1b = xb + NX;
  __hip_bfloat16* w2b = w1b + NW1;
  __hip_bfloat16* q   = w2b + NW2;
  __hip_bfloat16* k   = q + NX;
  __hip_bfloat16* vr  = k + NX;     // [bh][s][d] row-major v
  __hip_bfloat16* vst = vr + NX;    // [bh][64][256] compressed V^T
  __hip_bfloat16* ks  = vst + NVS;  // [bh][256][64] compressed K rows
  // total ws: (4*NX + NW1 + NW2 + 2*NVS)*2 B ~= 31 MB

  // fused fp32 -> bf16 converts (xb|w1b|w2b contiguous)
  const int na4 = (int)(NX / 4), nb4 = (int)(NW1 / 4), nc4 = (int)(NW2 / 4);
  cvt3_f32_bf16<<<dim3((na4 + nb4 + nc4) / 256), 256, 0, stream>>>(
      x, qkvw, outw, xb, na4, nb4);

  gemm_qkv<<<dim3(2304 / 128, 4096 / 128), 256, 0, stream>>>(
      xb, w1b, qkvb, q, k, vr, vst, ks, 768);

  // fused attention + out-projection: 256 blocks x 12 waves (one per head)
  attn_out<<<dim3(2 * S_ / 16), 768, 0, stream>>>(
      q, k, ks, vr, vst, w2b, outb, out);
}

// Round 10
// 148.175 us; speedup vs baseline: 1.1330x; 1.1330x over previous
//
#include <hip/hip_runtime.h>
#include <hip/hip_bf16.h>
#include <stdint.h>

// Problem constants (UniformStrideAttention): B=2, S=2048, D=768, H=12, HD=64, STRIDE=8
#define H_   12
#define S_   2048
#define D_   768
#define HD_  64
#define MS_  256   // S_/8 compressed strided keys per head

typedef __bf16 bf16_8 __attribute__((ext_vector_type(8)));
typedef float  f32_4  __attribute__((ext_vector_type(4)));

typedef __attribute__((address_space(1))) void* gas_ptr;
typedef __attribute__((address_space(3))) void* las_ptr;

__device__ __forceinline__ void g2l16(const void* g, void* l) {
  __builtin_amdgcn_global_load_lds((gas_ptr)g, (las_ptr)l, 16, 0, 0);
}

__device__ __forceinline__ f32_4 mfma16(bf16_8 a, bf16_8 b, f32_4 c) {
  return __builtin_amdgcn_mfma_f32_16x16x32_bf16(a, b, c, 0, 0, 0);
}

__device__ __forceinline__ bf16_8 ld8(const __hip_bfloat16* p) {
  return *reinterpret_cast<const bf16_8*>(p);
}

// ---------------------------------------------------------------------------
// Fused fp32 -> bf16 convert for all three GEMM inputs (x, qkv_w, out_w).
// Destinations are CONTIGUOUS in ws (xb | w1b | w2b), so output index == t.
// ---------------------------------------------------------------------------
__global__ __launch_bounds__(256) void cvt3_f32_bf16(
    const float* __restrict__ a, const float* __restrict__ b,
    const float* __restrict__ c, __hip_bfloat16* __restrict__ out,
    int na4, int nb4) {
  const int t = blockIdx.x * 256 + threadIdx.x;
  float4 f;
  if (t < na4)            f = reinterpret_cast<const float4*>(a)[t];
  else if (t < na4 + nb4) f = reinterpret_cast<const float4*>(b)[t - na4];
  else                    f = reinterpret_cast<const float4*>(c)[t - na4 - nb4];
  union { __hip_bfloat16 h[4]; ushort4 u; } p;
  p.h[0] = __float2bfloat16(f.x);
  p.h[1] = __float2bfloat16(f.y);
  p.h[2] = __float2bfloat16(f.z);
  p.h[3] = __float2bfloat16(f.w);
  reinterpret_cast<ushort4*>(out)[t] = p.u;
}

// ---------------------------------------------------------------------------
// C[M,N] = A[M,K] * B[N,K]^T + bias[N]   (bf16 in, fp32 MFMA accum, fp32 bias)
// Tile 128 x BN, BK=32; 4 waves as 2x2 of 64 x BN/2; 16x16x32 MFMA.
// MODE 0 (BN=128): QKV epilogue -> q/k/v row-major [bh][s][d] + compressed
//   Ks[bh][s/8][d] (t==1, s%8==0) + VsT[bh][d][s/8] (t==2, s%8==0).
// MODE 1: plain epilogue -> OF[M,N] fp32. BN=64: 2x grid for small N.
// ---------------------------------------------------------------------------
template <int MODE, int BN>
__global__ __launch_bounds__(256, 2) void gemm_bt(
    const __hip_bfloat16* __restrict__ A, const __hip_bfloat16* __restrict__ B,
    const float* __restrict__ bias,
    __hip_bfloat16* __restrict__ O0, __hip_bfloat16* __restrict__ O1,
    __hip_bfloat16* __restrict__ O2, __hip_bfloat16* __restrict__ O3,
    __hip_bfloat16* __restrict__ O4, float* __restrict__ OF,
    int M, int N, int K) {
  constexpr int NTJ = BN / 32;
  __shared__ __bf16 sA[128 * 32];
  __shared__ __bf16 sB[BN * 32];
  const int tid  = threadIdx.x;
  const int lane = tid & 63;
  const int wv   = tid >> 6;
  const int m0 = blockIdx.y * 128;
  const int n0 = blockIdx.x * BN;
  const int wr = (wv >> 1) * 64;
  const int wc = (wv & 1) * (BN / 2);

  f32_4 acc[4][NTJ] = {};

  const __hip_bfloat16* aS = A + (size_t)(m0 + (tid >> 2)) * K + ((tid & 3) << 3);
  const __hip_bfloat16* bS = B + (size_t)(n0 + (tid >> 2)) * K + ((tid & 3) << 3);
  const size_t half = (size_t)64 * K;
  __bf16* dA  = &sA[tid * 8];
  __bf16* dA2 = &sA[tid * 8 + 2048];
  __bf16* dB  = &sB[tid * 8];
  __bf16* dB2 = &sB[tid * 8 + 2048];

  const int fr = lane & 15;
  const int kq = (lane >> 4) << 3;

  for (int k0 = 0; k0 < K; k0 += 32) {
    g2l16(aS, dA);
    g2l16(aS + half, dA2);
    g2l16(bS, dB);
    if constexpr (BN == 128) g2l16(bS + half, dB2);
    aS += 32;
    bS += 32;
    __syncthreads();
    bf16_8 af[4], bfm[NTJ];
#pragma unroll
    for (int t = 0; t < 4; ++t)
      af[t] = *reinterpret_cast<const bf16_8*>(&sA[(wr + t * 16 + fr) * 32 + kq]);
#pragma unroll
    for (int t = 0; t < NTJ; ++t)
      bfm[t] = *reinterpret_cast<const bf16_8*>(&sB[(wc + t * 16 + fr) * 32 + kq]);
#pragma unroll
    for (int ti = 0; ti < 4; ++ti)
#pragma unroll
      for (int tj = 0; tj < NTJ; ++tj)
        acc[ti][tj] = mfma16(af[ti], bfm[tj], acc[ti][tj]);
    __syncthreads();
  }

  // epilogue: C/D layout col=lane&15, row=(lane>>4)*4+reg
  const int crow = (lane >> 4) << 2;
  const int ccol = lane & 15;
#pragma unroll
  for (int ti = 0; ti < 4; ++ti) {
    const int gmb = m0 + wr + ti * 16 + crow;
#pragma unroll
    for (int tj = 0; tj < NTJ; ++tj) {
      const int gn = n0 + wc + tj * 16 + ccol;
      const float bv = bias[gn];
      if (MODE == 0) {
        const int t   = gn / D_;
        const int rem = gn - t * D_;
        const int hh = rem >> 6, dd = rem & 63;
        __hip_bfloat16* dst = (t == 0) ? O0 : (t == 1) ? O1 : O2;
#pragma unroll
        for (int r = 0; r < 4; ++r) {
          const int gm = gmb + r;
          const int bb = gm >> 11, ss = gm & (S_ - 1);
          const __hip_bfloat16 hv = __float2bfloat16(acc[ti][tj][r] + bv);
          dst[(((size_t)(bb * H_ + hh) << 11) + ss) * HD_ + dd] = hv;
          if (r == 0 && (gmb & 7) == 0) {
            if (t == 1)        // compressed K rows for coalesced strided reads
              O4[(((size_t)(bb * H_ + hh)) * MS_ + (ss >> 3)) * HD_ + dd] = hv;
            else if (t == 2)   // compressed V^T (d-major) for strided PV
              O3[((size_t)(bb * H_ + hh) * HD_ + dd) * MS_ + (ss >> 3)] = hv;
          }
        }
      } else {
#pragma unroll
        for (int r = 0; r < 4; ++r)
          OF[(size_t)(gmb + r) * D_ + gn] = acc[ti][tj][r] + bv;
      }
    }
  }
}

// ---------------------------------------------------------------------------
// MFMA strided attention, NO-RESCALE softmax, 2-WAVE K-SPLIT per task.
// Because the no-rescale softmax makes O and L additive over chunks, each
// (head, 16-row) task is split across 2 waves: part 0 = even strided chunks,
// part 1 = odd strided chunks + local band {i-1,i}\{mult of 8}. Part 1 dumps
// fp32 partials to LDS; one barrier; part 0 combines, normalizes, writes ctx.
// Halves the serial per-wave chunk chain (the latency critical path) and
// doubles wave-level parallelism (6144 waves). Chunk bodies = R8 verbatim.
// ---------------------------------------------------------------------------
__global__ __launch_bounds__(256) void attn_mfma(
    const __hip_bfloat16* __restrict__ Q, const __hip_bfloat16* __restrict__ Kb,
    const __hip_bfloat16* __restrict__ Ks, const __hip_bfloat16* __restrict__ Vr,
    const __hip_bfloat16* __restrict__ VsT, __hip_bfloat16* __restrict__ ctx) {
  __shared__ __bf16 pt[4][16 * 40];
  __shared__ float ox[2][64][20];   // part-1 partials: 16 O + 4 L per lane
  const int lane = threadIdx.x & 63;
  const int wv   = threadIdx.x >> 6;
  const int tp   = wv >> 1;                 // in-block task index (0/1)
  const int part = wv & 1;                  // K-split half
  const int task = blockIdx.x * 2 + tp;     // 3072 tasks = bh*128 + qtile
  const int bh   = task >> 7;
  const int i0   = (task & 127) << 4;       // first of 16 query rows
  const int lr   = lane & 15;
  const int quad = lane >> 4;
  const float SC = 0.125f * 1.44269504088896340736f;  // 1/sqrt(64)*log2(e)

  const __hip_bfloat16* Kh  = Kb  + ((size_t)bh << 11) * HD_;
  const __hip_bfloat16* Ksh = Ks  + (size_t)bh * MS_ * HD_;
  const __hip_bfloat16* Vrh = Vr  + ((size_t)bh << 11) * HD_;
  const __hip_bfloat16* Vsh = VsT + (size_t)bh * HD_ * MS_;
  __bf16* ptw = pt[wv];

  const int jbase = (i0 >= 8) ? (i0 - 8) : 0;   // local band base (8-aligned)

  // --- part 1 only: early band loads (latency hides behind strided loop) ---
  bf16_8 vfb[4], kb_[2][2];
  if (part) {
    const __bf16* Vrb = reinterpret_cast<const __bf16*>(Vrh);
#pragma unroll
    for (int ct = 0; ct < 4; ++ct)
#pragma unroll
      for (int e = 0; e < 8; ++e) {
        const int j  = jbase + quad * 8 + e;
        const int jr = (j < S_) ? j : (S_ - 1);   // clamp; masked via P=0
        vfb[ct][e] = Vrb[(size_t)jr * HD_ + ct * 16 + lr];
      }
#pragma unroll
    for (int t = 0; t < 2; ++t) {
      const int j  = jbase + t * 16 + lr;
      const int jr = (j < S_) ? j : (S_ - 1);
      const __hip_bfloat16* kp = Kh + (size_t)jr * HD_ + quad * 8;
      kb_[t][0] = ld8(kp);
      kb_[t][1] = ld8(kp + 32);
    }
  }

  // Q A-frags: row = i0+lr, k = quad*8 (+32)
  const __hip_bfloat16* qp = Q + (((size_t)bh << 11) + i0 + lr) * HD_ + quad * 8;
  const bf16_8 qf0 = ld8(qp);
  const bf16_8 qf1 = ld8(qp + 32);

  const __bf16 one = (__bf16)1.0f;
  const bf16_8 onesf = {one, one, one, one, one, one, one, one};

  f32_4 Lacc = {}, oacc[4];
#pragma unroll
  for (int ct = 0; ct < 4; ++ct) oacc[ct] = f32_4{0.f, 0.f, 0.f, 0.f};

  const int mmax = (i0 + 15) >> 3;
  const int nstr = (mmax >> 5) + 1;   // strided 32-key chunks

  auto load_str = [&](int c, bf16_8 (&kf)[2][2], bf16_8 (&vf)[4]) {
    const int mb = c << 5;
#pragma unroll
    for (int t = 0; t < 2; ++t) {
      const __hip_bfloat16* kp = Ksh + (size_t)(mb + t * 16 + lr) * HD_ + quad * 8;
      kf[t][0] = ld8(kp);
      kf[t][1] = ld8(kp + 32);
    }
#pragma unroll
    for (int ct = 0; ct < 4; ++ct)
      vf[ct] = ld8(Vsh + (size_t)(ct * 16 + lr) * MS_ + mb + quad * 8);
  };

  auto softmax_pv = [&](f32_4& s0, f32_4& s1, const bf16_8 (&vf)[4]) {
#pragma unroll
    for (int r = 0; r < 4; ++r) {
      const int row = quad * 4 + r;
      ptw[row * 40 + lr]      = (__bf16)__float2bfloat16(s0[r]);
      ptw[row * 40 + 16 + lr] = (__bf16)__float2bfloat16(s1[r]);
    }
    const bf16_8 pf = *reinterpret_cast<const bf16_8*>(&ptw[lr * 40 + quad * 8]);
#pragma unroll
    for (int ct = 0; ct < 4; ++ct) oacc[ct] = mfma16(pf, vf[ct], oacc[ct]);
    Lacc = mfma16(pf, onesf, Lacc);
  };

  // --- this part's strided chunks (stride 2, prefetched) ---
  bf16_8 kf[2][2], vf[4], kf2[2][2], vf2[4];
  if (part < nstr) load_str(part, kf, vf);
  for (int c = part; c < nstr; c += 2) {
    const bool more = (c + 2 < nstr);
    if (more) load_str(c + 2, kf2, vf2);
    const int mb = c << 5;

    f32_4 s0 = {}, s1 = {};
    s0 = mfma16(qf0, kf[0][0], s0);
    s0 = mfma16(qf1, kf[0][1], s0);
    s1 = mfma16(qf0, kf[1][0], s1);
    s1 = mfma16(qf1, kf[1][1], s1);

#pragma unroll
    for (int r = 0; r < 4; ++r) {
      const int i = i0 + quad * 4 + r;
      const bool v0 = ((mb + lr) << 3) <= i;
      const bool v1 = ((mb + 16 + lr) << 3) <= i;
      s0[r] = v0 ? exp2f(fminf(s0[r] * SC, 63.f)) : 0.f;
      s1[r] = v1 ? exp2f(fminf(s1[r] * SC, 63.f)) : 0.f;
    }
    softmax_pv(s0, s1, vf);

    if (more) {
#pragma unroll
      for (int t = 0; t < 2; ++t) { kf[t][0] = kf2[t][0]; kf[t][1] = kf2[t][1]; }
#pragma unroll
      for (int ct = 0; ct < 4; ++ct) vf[ct] = vf2[ct];
    }
  }

  // --- part 1: local band chunk {i-1,i} \ multiples-of-8, then dump ---
  if (part) {
    f32_4 s0 = {}, s1 = {};
    s0 = mfma16(qf0, kb_[0][0], s0);
    s0 = mfma16(qf1, kb_[0][1], s0);
    s1 = mfma16(qf0, kb_[1][0], s1);
    s1 = mfma16(qf1, kb_[1][1], s1);

#pragma unroll
    for (int r = 0; r < 4; ++r) {
      const int i = i0 + quad * 4 + r;
      const int j0 = jbase + lr, j1 = jbase + 16 + lr;
      const bool v0 = (j0 == i || j0 == i - 1) && (j0 & 7);
      const bool v1 = (j1 == i || j1 == i - 1) && (j1 & 7);
      s0[r] = v0 ? exp2f(fminf(s0[r] * SC, 63.f)) : 0.f;
      s1[r] = v1 ? exp2f(fminf(s1[r] * SC, 63.f)) : 0.f;
    }
    softmax_pv(s0, s1, vfb);

#pragma unroll
    for (int ct = 0; ct < 4; ++ct)
#pragma unroll
      for (int r = 0; r < 4; ++r) ox[tp][lane][ct * 4 + r] = oacc[ct][r];
#pragma unroll
    for (int r = 0; r < 4; ++r) ox[tp][lane][16 + r] = Lacc[r];
  }
  __syncthreads();

  // --- part 0: combine partials, normalize, write ctx[b][s][h*64+d] ---
  if (!part) {
#pragma unroll
    for (int ct = 0; ct < 4; ++ct)
#pragma unroll
      for (int r = 0; r < 4; ++r) oacc[ct][r] += ox[tp][lane][ct * 4 + r];
#pragma unroll
    for (int r = 0; r < 4; ++r) Lacc[r] += ox[tp][lane][16 + r];

    const int b = bh / H_;
    const int h = bh - b * H_;
    f32_4 inv;
#pragma unroll
    for (int r = 0; r < 4; ++r) inv[r] = 1.f / Lacc[r];
#pragma unroll
    for (int r = 0; r < 4; ++r) {
      const int i = i0 + quad * 4 + r;
      __hip_bfloat16* cp = ctx + ((size_t)(b * S_ + i)) * D_ + h * HD_ + lr;
#pragma unroll
      for (int ct = 0; ct < 4; ++ct)
        cp[ct * 16] = __float2bfloat16(oacc[ct][r] * inv[r]);
    }
  }
}

// ---------------------------------------------------------------------------
extern "C" void kernel_launch(void* const* d_in, const int* in_sizes, int n_in,
                              void* d_out, int out_size, void* d_ws, size_t ws_size,
                              hipStream_t stream) {
  const float* x    = (const float*)d_in[0];  // [B,S,D]    fp32
  const float* qkvw = (const float*)d_in[1];  // [3D,D]     fp32
  const float* qkvb = (const float*)d_in[2];  // [3D]       fp32
  const float* outw = (const float*)d_in[3];  // [D,D]      fp32
  const float* outb = (const float*)d_in[4];  // [D]        fp32
  float* out = (float*)d_out;                 // [B,S,D]    fp32

  const size_t NX  = (size_t)2 * S_ * D_;     // 3,145,728
  const size_t NW1 = (size_t)3 * D_ * D_;     // 1,769,472
  const size_t NW2 = (size_t)D_ * D_;         //   589,824
  const size_t NVS = (size_t)2 * H_ * HD_ * MS_;  // 393,216

  __hip_bfloat16* xb  = (__hip_bfloat16*)d_ws;
  __hip_bfloat16* w1b = xb + NX;
  __hip_bfloat16* w2b = w1b + NW1;
  __hip_bfloat16* q   = w2b + NW2;
  __hip_bfloat16* k   = q + NX;
  __hip_bfloat16* vr  = k + NX;     // [bh][s][d] row-major v
  __hip_bfloat16* vst = vr + NX;    // [bh][64][256] compressed V^T
  __hip_bfloat16* ks  = vst + NVS;  // [bh][256][64] compressed K rows
  __hip_bfloat16* ctx = ks + NVS;   // [B,S,H*HD]
  // total ws: (5*NX + NW1 + NW2 + 2*NVS)*2 B ~= 37.3 MB

  // fused fp32 -> bf16 converts (xb|w1b|w2b contiguous)
  const int na4 = (int)(NX / 4), nb4 = (int)(NW1 / 4), nc4 = (int)(NW2 / 4);
  cvt3_f32_bf16<<<dim3((na4 + nb4 + nc4) / 256), 256, 0, stream>>>(
      x, qkvw, outw, xb, na4, nb4);

  gemm_bt<0, 128><<<dim3(2304 / 128, 4096 / 128), 256, 0, stream>>>(
      xb, w1b, qkvb, q, k, vr, vst, ks, nullptr, 4096, 2304, 768);

  // 3072 tasks x 2 waves each; 256-thread blocks hold 2 tasks -> 1536 blocks
  attn_mfma<<<dim3(2 * H_ * S_ / 16 / 2), 256, 0, stream>>>(
      q, k, ks, vr, vst, ctx);

  // out-proj: BN=64 -> 12x32 = 384 blocks on 256 CUs
  gemm_bt<1, 64><<<dim3(768 / 64, 4096 / 128), 256, 0, stream>>>(
      ctx, w2b, outb, nullptr, nullptr, nullptr, nullptr, nullptr,
      out, 4096, 768, 768);
}